// Round 5
// baseline (995.575 us; speedup 1.0000x reference)
//
#include <hip/hip_runtime.h>
#include <hip/hip_bf16.h>
#include <cmath>

#define LAYERS 4
#define Bb 4
#define Ss 1024
#define Dd 1024
#define Ff 2048
#define Hh 8
#define DHd 128
#define Mm (Bb * Ss)   // 4096 rows
#define EPSf 1e-5f

typedef __attribute__((ext_vector_type(8))) short short8v;
typedef __attribute__((ext_vector_type(4))) float f32x4;
typedef __attribute__((ext_vector_type(4))) unsigned int u32x4;

__device__ __forceinline__ float swish_f(float x) { return x / (1.f + expf(-x)); }
__device__ __forceinline__ float gelu_f(float x) {
  return 0.5f * x * (1.f + tanhf(0.7978845608028654f * (x + 0.044715f * x * x * x)));
}
__device__ __forceinline__ unsigned short f2bfu(float f) {
  __hip_bfloat16 h = __float2bfloat16(f);
  return __builtin_bit_cast(unsigned short, h);
}
__device__ __forceinline__ float bfu2f(unsigned short u) {
  unsigned v = ((unsigned)u) << 16;
  return __builtin_bit_cast(float, v);
}
__device__ __forceinline__ void gl_lds16(const void* g, void* l) {
  __builtin_amdgcn_global_load_lds((__attribute__((address_space(1))) void*)g,
                                   (__attribute__((address_space(3))) void*)l, 16, 0, 0);
}
__device__ __forceinline__ f32x4 mfma16(short8v a, short8v b, f32x4 c) {
  return __builtin_amdgcn_mfma_f32_16x16x32_bf16(a, b, c, 0, 0, 0);
}

// ---------------- LayerNorm fp32 -> bf16 ----------------
__global__ __launch_bounds__(256) void ln_bf16_kernel(const float* __restrict__ x,
                                                      short* __restrict__ outb,
                                                      const float* __restrict__ sc,
                                                      const float* __restrict__ bi) {
  const int row = blockIdx.x;
  const int t = threadIdx.x;
  const float4 v = *(const float4*)(x + (size_t)row * Dd + t * 4);
  float s = v.x + v.y + v.z + v.w;
  float s2 = v.x * v.x + v.y * v.y + v.z * v.z + v.w * v.w;
#pragma unroll
  for (int o = 32; o > 0; o >>= 1) { s += __shfl_down(s, o); s2 += __shfl_down(s2, o); }
  __shared__ float ps[4], ps2[4];
  if ((t & 63) == 0) { ps[t >> 6] = s; ps2[t >> 6] = s2; }
  __syncthreads();
  s = ps[0] + ps[1] + ps[2] + ps[3];
  s2 = ps2[0] + ps2[1] + ps2[2] + ps2[3];
  const float mu = s * (1.f / Dd);
  const float var = s2 * (1.f / Dd) - mu * mu;
  const float rstd = rsqrtf(var + EPSf);
  const float4 g = *(const float4*)(sc + t * 4);
  const float4 b = *(const float4*)(bi + t * 4);
  const float o0 = (v.x - mu) * rstd * g.x + b.x;
  const float o1 = (v.y - mu) * rstd * g.y + b.y;
  const float o2 = (v.z - mu) * rstd * g.z + b.z;
  const float o3 = (v.w - mu) * rstd * g.w + b.w;
  unsigned p0 = (unsigned)f2bfu(o0) | ((unsigned)f2bfu(o1) << 16);
  unsigned p1 = (unsigned)f2bfu(o2) | ((unsigned)f2bfu(o3) << 16);
  uint2 pk; pk.x = p0; pk.y = p1;
  *(uint2*)(outb + (size_t)row * Dd + t * 4) = pk;
}

// ---------------- RoPE tables ----------------
__global__ void rope_table_kernel(float* __restrict__ ct, float* __restrict__ st) {
  const int i = blockIdx.x * 256 + threadIdx.x;  // < Ss*64
  const int s = i >> 6, f = i & 63;
  const float inv = powf(10000.f, -(float)f / 64.f);
  const float a = (float)s * inv;
  ct[i] = cosf(a);
  st[i] = sinf(a);
}

// ---------------- RoPE apply fp32 -> bf16 (Q:+sin, K:-sin) ----------------
__global__ void rope_bf16_kernel(const float* __restrict__ Qf, const float* __restrict__ Kf,
                                 short* __restrict__ Qo, short* __restrict__ Ko,
                                 const float* __restrict__ ct, const float* __restrict__ st) {
  const int idx = blockIdx.x * 256 + threadIdx.x;  // < B*S*H*64 pairs
  const int f = idx & 63;
  const int s = (idx >> 9) & (Ss - 1);
  const size_t base = (size_t)(idx >> 6) * DHd + 2 * f;
  const float c = ct[(s << 6) + f], sn = st[(s << 6) + f];
  const float2 q = *(const float2*)(Qf + base);
  const float2 k = *(const float2*)(Kf + base);
  unsigned qp = (unsigned)f2bfu(q.x * c - q.y * sn) | ((unsigned)f2bfu(q.x * sn + q.y * c) << 16);
  unsigned kp = (unsigned)f2bfu(k.x * c + k.y * sn) | ((unsigned)f2bfu(-k.x * sn + k.y * c) << 16);
  *(unsigned*)(Qo + base) = qp;
  *(unsigned*)(Ko + base) = kp;
}

// ---------------- transpose-convert QKVG concat: 4x W[K][1024] fp32 -> Wt[4096][K] bf16 ----
__global__ __launch_bounds__(256) void wtrans4_kernel(const float* __restrict__ W0,
                                                      const float* __restrict__ W1,
                                                      const float* __restrict__ W2,
                                                      const float* __restrict__ W3,
                                                      short* __restrict__ Wt) {
  __shared__ float tile[32][33];
  const int t = threadIdx.x;
  const int n0 = blockIdx.x * 32, k0 = blockIdx.y * 32;
  const int which = n0 >> 10;
  const float* W = (which == 0) ? W0 : (which == 1) ? W1 : (which == 2) ? W2 : W3;
  const int nl = n0 & 1023;
  const int tc = t & 31, tr8 = t >> 5;
#pragma unroll
  for (int i = 0; i < 4; ++i) {
    const int r = tr8 + i * 8;
    tile[r][tc] = W[(size_t)(k0 + r) * 1024 + nl + tc];
  }
  __syncthreads();
#pragma unroll
  for (int i = 0; i < 4; ++i) {
    const int r = tr8 + i * 8;
    Wt[(size_t)(n0 + r) * 1024 + k0 + tc] = (short)f2bfu(tile[tc][r]);
  }
}

// ---------------- transpose-convert single: W[K][N] fp32 -> Wt[N][K] bf16 ----------------
__global__ __launch_bounds__(256) void wtrans1_kernel(const float* __restrict__ W,
                                                      short* __restrict__ Wt, int K, int N) {
  __shared__ float tile[32][33];
  const int t = threadIdx.x;
  const int n0 = blockIdx.x * 32, k0 = blockIdx.y * 32;
  const int tc = t & 31, tr8 = t >> 5;
#pragma unroll
  for (int i = 0; i < 4; ++i) {
    const int r = tr8 + i * 8;
    tile[r][tc] = W[(size_t)(k0 + r) * N + n0 + tc];
  }
  __syncthreads();
#pragma unroll
  for (int i = 0; i < 4; ++i) {
    const int r = tr8 + i * 8;
    Wt[(size_t)(n0 + r) * K + k0 + tc] = (short)f2bfu(tile[tc][r]);
  }
}

// ---------------- V transpose bf16: Vb [B*S][D-slice h] -> Vt [(bh*128+d)][S] ----------------
__global__ __launch_bounds__(256) void vtrans16_kernel(const short* __restrict__ Vb,
                                                       short* __restrict__ Vt) {
  __shared__ short tile[32][33];
  const int t = threadIdx.x;
  const int s0 = blockIdx.x * 32, d0 = blockIdx.y * 32, bh = blockIdx.z;
  const int bb = bh >> 3, h = bh & 7;
  const int tc = t & 31, tr8 = t >> 5;
#pragma unroll
  for (int i = 0; i < 4; ++i) {
    const int r = tr8 + i * 8;
    tile[r][tc] = Vb[(size_t)(bb * Ss + s0 + r) * Dd + h * DHd + d0 + tc];
  }
  __syncthreads();
#pragma unroll
  for (int i = 0; i < 4; ++i) {
    const int r = tr8 + i * 8;
    Vt[(size_t)(bh * DHd + d0 + r) * Ss + s0 + tc] = tile[tc][r];
  }
}

// ---------------- bf16 MFMA GEMM v5: ring-4 LDS, counted vmcnt, 1 barrier/K-step ----------
// Wave grid NWM x NWC (NTHR = NWM*NWC*64). BK=32. XOR chunk swizzle both operands.
// EPI: 0 = QKVG route (Q,K fp32; V,G bf16), 1 = +Res fp32, 2 = gelu bf16
template <int BM, int BN, int NWM, int NWC, int EPI>
__global__ __launch_bounds__(NWM * NWC * 64) void gemm5(
    const short* __restrict__ A, const short* __restrict__ Bt,
    float* __restrict__ Cf, short* __restrict__ Cb, const float* __restrict__ Res,
    float* __restrict__ Qf, float* __restrict__ Kf,
    short* __restrict__ Vb, short* __restrict__ Gb, int N, int K) {
  constexpr int NTHR = NWM * NWC * 64;
  constexpr int WM = BM / NWM, WN = BN / NWC;
  constexpr int MR = WM / 16, NR = WN / 16;
  constexpr int LA = (BM * 4) / NTHR, LB = (BN * 4) / NTHR;
  constexpr int LT = LA + LB;
  __shared__ __align__(16) short As[4][BM * 32];
  __shared__ __align__(16) short Bs[4][BN * 32];
  const int t = threadIdx.x;
  const int w = t >> 6, l = t & 63;
  const int lq = l >> 4, lr = l & 15;
  const int wr = w / NWC, wc = w % NWC;
  // T1: bijective XCD swizzle (nwg % 8 == 0 for all grids here)
  const int nwg = gridDim.x * gridDim.y;
  const int bid0 = blockIdx.x + blockIdx.y * gridDim.x;
  const int lgid = (bid0 & 7) * (nwg >> 3) + (bid0 >> 3);
  const int bx = lgid % gridDim.x, by = lgid / gridDim.x;
  const int row0 = by * BM, col0 = bx * BN;
  f32x4 acc[MR][NR] = {};
  const int NTK = K >> 5;

  auto stage = [&](int tile) {
    const int rg = tile & 3;
    const int k0 = tile << 5;
#pragma unroll
    for (int i = 0; i < LA; ++i) {
      const int c = t + i * NTHR;
      const int row = c >> 2, sc = c & 3;
      gl_lds16(A + (size_t)(row0 + row) * K + k0 + ((sc ^ (row & 3)) << 3),
               &As[rg][(w * 64 + i * NTHR) * 8]);
    }
#pragma unroll
    for (int i = 0; i < LB; ++i) {
      const int c = t + i * NTHR;
      const int row = c >> 2, sc = c & 3;
      gl_lds16(Bt + (size_t)(col0 + row) * K + k0 + ((sc ^ (row & 3)) << 3),
               &Bs[rg][(w * 64 + i * NTHR) * 8]);
    }
  };

  stage(0); stage(1); stage(2);
  for (int tt = 0; tt < NTK; ++tt) {
    const int rem = NTK - 1 - tt;
    // counted vmcnt + raw barrier: tile tt guaranteed landed, newer stages stay in flight
    if (rem >= 2) {
      asm volatile("s_waitcnt vmcnt(%0)\n\ts_barrier" :: "n"(2 * LT) : "memory");
    } else if (rem == 1) {
      asm volatile("s_waitcnt vmcnt(%0)\n\ts_barrier" :: "n"(LT) : "memory");
    } else {
      asm volatile("s_waitcnt vmcnt(0)\n\ts_barrier" ::: "memory");
    }
    if (tt + 3 < NTK) stage(tt + 3);  // overwrites slot of tile tt-1 (reads done pre-barrier)
    const int rg = tt & 3;
    short8v a[MR], b[NR];
#pragma unroll
    for (int m = 0; m < MR; ++m) {
      const int row = wr * WM + m * 16 + lr;
      a[m] = *(const short8v*)&As[rg][row * 32 + ((lq ^ (row & 3)) << 3)];
    }
#pragma unroll
    for (int n = 0; n < NR; ++n) {
      const int col = wc * WN + n * 16 + lr;
      b[n] = *(const short8v*)&Bs[rg][col * 32 + ((lq ^ (col & 3)) << 3)];
    }
    __builtin_amdgcn_s_setprio(1);
#pragma unroll
    for (int m = 0; m < MR; ++m)
#pragma unroll
      for (int n = 0; n < NR; ++n) acc[m][n] = mfma16(a[m], b[n], acc[m][n]);
    __builtin_amdgcn_s_setprio(0);
  }

  const int sel = col0 >> 10;  // for EPI 0
  const int clb = col0 & 1023;
#pragma unroll
  for (int m = 0; m < MR; ++m) {
#pragma unroll
    for (int n = 0; n < NR; ++n) {
#pragma unroll
      for (int r = 0; r < 4; ++r) {
        const int row = row0 + wr * WM + m * 16 + lq * 4 + r;
        const int col = col0 + wc * WN + n * 16 + lr;
        float v = acc[m][n][r];
        if (EPI == 0) {
          const int cl = clb + wc * WN + n * 16 + lr;
          const size_t o = (size_t)row * 1024 + cl;
          if (sel == 0) Qf[o] = v;
          else if (sel == 1) Kf[o] = v;
          else if (sel == 2) Vb[o] = (short)f2bfu(v);
          else Gb[o] = (short)f2bfu(v);
        } else {
          const size_t o = (size_t)row * N + col;
          if (EPI == 1) Cf[o] = v + Res[o];
          else Cb[o] = (short)f2bfu(gelu_f(v));
        }
      }
    }
  }
}

// ---------------- Retention v4: dbuf K/V, 1 barrier/tile, setprio, XCD-local bh ----------
__global__ __launch_bounds__(256) void ret4_kernel(const short* __restrict__ Qb,
                                                   const short* __restrict__ Kb,
                                                   const short* __restrict__ Vt,
                                                   float* __restrict__ Y0,
                                                   float* __restrict__ Y1) {
  __shared__ __align__(16) short Ks[2][64 * 128];
  __shared__ __align__(16) short Vs[2][128 * 64];
  const int t = threadIdx.x, w = t >> 6, l = t & 63;
  const int lq = l >> 4, lr = l & 15;
  const int u = blockIdx.x;                 // 0..511
  const int lgid = (u & 7) * 64 + (u >> 3);
  const int half = lgid >> 8;
  const int rest = lgid & 255;
  const int bh = rest >> 3, j = rest & 7;
  const int qb = half ? j : 7 - j;          // dispatch-order-balanced triangular pairing
  const int b = bh >> 3, h = bh & 7;
  const int q0 = qb * 128;
  const float lstep = (logf(1.f / 512.f) - logf(1.f / 32.f)) * (1.f / 7.f);
  const float gamma = 1.f - expf(logf(1.f / 32.f) + (float)h * lstep);
  const float l2g = logf(gamma) * 1.44269504f;  // log2(gamma)

  short8v qf[2][4];
#pragma unroll
  for (int qn = 0; qn < 2; ++qn)
#pragma unroll
    for (int ks = 0; ks < 4; ++ks)
      qf[qn][ks] = *(const short8v*)(Qb + (size_t)(b * Ss + q0 + w * 32 + qn * 16 + lr) * Dd +
                                     h * DHd + ks * 32 + lq * 8);

  float cmf[4], csr[4];
#pragma unroll
  for (int mf = 0; mf < 4; ++mf) cmf[mf] = exp2f(l2g * (float)(-16 * mf));
#pragma unroll
  for (int r = 0; r < 4; ++r) csr[r] = exp2f(l2g * (float)(63 - 4 * lq - r));

  f32x4 yacc[2][8] = {};
  const int nt = 2 * qb + 2;
  const int sb = ((lq & 1) * 2) * 16 + lr;

  auto stageKV = [&](int m0, int buf) {
#pragma unroll
    for (int i = 0; i < 4; ++i) {
      const int c = (w * 4 + i) * 64 + l;
      const int row = c >> 4, slot = c & 15;
      gl_lds16(Kb + (size_t)(b * Ss + m0 + row) * Dd + h * DHd + ((slot ^ (row & 7)) * 8),
               &Ks[buf][(w * 4 + i) * 512]);
    }
#pragma unroll
    for (int i = 0; i < 4; ++i) {
      const int c = (w * 4 + i) * 64 + l;
      const int row = c >> 3, slot = c & 7;
      gl_lds16(Vt + (size_t)(bh * DHd + row) * Ss + m0 + ((slot ^ (row & 7)) * 8),
               &Vs[buf][(w * 4 + i) * 512]);
    }
  };

  stageKV(half * 64, 0);
  __syncthreads();
  int cur = 0;
  for (int tt = half; tt < nt; tt += 2) {
    const int m0 = tt * 64;
    if (tt + 2 < nt) stageKV((tt + 2) * 64, cur ^ 1);

    f32x4 st[4][2] = {};
    __builtin_amdgcn_s_setprio(1);
#pragma unroll
    for (int mf = 0; mf < 4; ++mf) {
      const int row = mf * 16 + lr;
#pragma unroll
      for (int ks = 0; ks < 4; ++ks) {
        short8v kf = *(const short8v*)&Ks[cur][row * 128 + (((4 * ks + lq) ^ (row & 7)) * 8)];
        st[mf][0] = mfma16(kf, qf[0][ks], st[mf][0]);
        st[mf][1] = mfma16(kf, qf[1][ks], st[mf][1]);
      }
    }
    __builtin_amdgcn_s_setprio(0);
    float rs[2];
#pragma unroll
    for (int qn = 0; qn < 2; ++qn)
      rs[qn] = exp2f(l2g * (float)(q0 + w * 32 + qn * 16 + lr - m0 - 63));
#pragma unroll
    for (int mf = 0; mf < 4; ++mf)
#pragma unroll
      for (int qn = 0; qn < 2; ++qn)
#pragma unroll
        for (int r = 0; r < 4; ++r) {
          const int qg = q0 + w * 32 + qn * 16 + lr;
          const int kvg = m0 + mf * 16 + lq * 4 + r;
          const float wgt = (qg >= kvg) ? rs[qn] * cmf[mf] * csr[r] : 0.f;
          st[mf][qn][r] *= wgt;
        }
    unsigned pk[4][2][2];
#pragma unroll
    for (int mf = 0; mf < 4; ++mf)
#pragma unroll
      for (int qn = 0; qn < 2; ++qn)
#pragma unroll
        for (int p = 0; p < 2; ++p)
          pk[mf][qn][p] = (unsigned)f2bfu(st[mf][qn][2 * p]) |
                          ((unsigned)f2bfu(st[mf][qn][2 * p + 1]) << 16);
    short8v afr[2][2];
#pragma unroll
    for (int qn = 0; qn < 2; ++qn)
#pragma unroll
      for (int ks2 = 0; ks2 < 2; ++ks2) {
        u32x4 wd;
#pragma unroll
        for (int wj = 0; wj < 4; ++wj) {
          const int src = sb + (wj >> 1) * 16;
          const unsigned v0 = __shfl(pk[2 * ks2 + 0][qn][wj & 1], src);
          const unsigned v1 = __shfl(pk[2 * ks2 + 1][qn][wj & 1], src);
          wd[wj] = (lq >= 2) ? v1 : v0;
        }
        afr[qn][ks2] = __builtin_bit_cast(short8v, wd);
      }
    __builtin_amdgcn_s_setprio(1);
#pragma unroll
    for (int nd = 0; nd < 8; ++nd) {
      const int row = nd * 16 + lr;
#pragma unroll
      for (int ks2 = 0; ks2 < 2; ++ks2) {
        short8v vf = *(const short8v*)&Vs[cur][row * 64 + (((4 * ks2 + lq) ^ (row & 7)) * 8)];
        yacc[0][nd] = mfma16(afr[0][ks2], vf, yacc[0][nd]);
        yacc[1][nd] = mfma16(afr[1][ks2], vf, yacc[1][nd]);
      }
    }
    __builtin_amdgcn_s_setprio(0);
    __syncthreads();
    cur ^= 1;
  }
  float* Y = half ? Y1 : Y0;
#pragma unroll
  for (int qn = 0; qn < 2; ++qn)
#pragma unroll
    for (int r = 0; r < 4; ++r) {
      const int q = q0 + w * 32 + qn * 16 + lq * 4 + r;
#pragma unroll
      for (int nd = 0; nd < 8; ++nd)
        Y[(size_t)(b * Ss + q) * Dd + h * DHd + nd * 16 + lr] = yacc[qn][nd][r];
    }
}

// ---------------- gate: Gb = bf16( swish(Graw) * GN(Y0+Y1) ) ----------------
__global__ __launch_bounds__(256) void gate_kernel(const float* __restrict__ Y0,
                                                   const float* __restrict__ Y1,
                                                   const short* __restrict__ Graw,
                                                   short* __restrict__ Gb,
                                                   const float* __restrict__ gs,
                                                   const float* __restrict__ gb) {
  const int lane = threadIdx.x & 63;
  const int rowh = blockIdx.x * 4 + (threadIdx.x >> 6);  // (b*S+s)*H + h
  const int h = rowh & 7;
  const size_t base = (size_t)(rowh >> 3) * Dd + (size_t)h * DHd + lane * 2;
  float2 a = *(const float2*)(Y0 + base);
  const float2 c = *(const float2*)(Y1 + base);
  a.x += c.x; a.y += c.y;
  float s = a.x + a.y, s2 = a.x * a.x + a.y * a.y;
#pragma unroll
  for (int o = 32; o > 0; o >>= 1) { s += __shfl_down(s, o); s2 += __shfl_down(s2, o); }
  s = __shfl(s, 0);
  s2 = __shfl(s2, 0);
  const float mu = s * (1.f / DHd);
  const float rstd = rsqrtf(s2 * (1.f / DHd) - mu * mu + EPSf);
  const int d = h * DHd + lane * 2;
  const float2 g = *(const float2*)(gs + d);
  const float2 bbv = *(const float2*)(gb + d);
  const float y0 = (a.x - mu) * rstd * g.x + bbv.x;
  const float y1 = (a.y - mu) * rstd * g.y + bbv.y;
  const unsigned gr = *(const unsigned*)(Graw + base);
  const float gx = bfu2f((unsigned short)(gr & 0xffff));
  const float gy = bfu2f((unsigned short)(gr >> 16));
  const unsigned o01 = (unsigned)f2bfu(swish_f(gx) * y0) |
                       ((unsigned)f2bfu(swish_f(gy) * y1) << 16);
  *(unsigned*)(Gb + base) = o01;
}

extern "C" void kernel_launch(void* const* d_in, const int* in_sizes, int n_in,
                              void* d_out, int out_size, void* d_ws, size_t ws_size,
                              hipStream_t stream) {
  const float* X = (const float*)d_in[0];
  const float* Wq = (const float*)d_in[1];
  const float* Wk = (const float*)d_in[2];
  const float* Wv = (const float*)d_in[3];
  const float* Wg = (const float*)d_in[4];
  const float* Wo = (const float*)d_in[5];
  const float* W1 = (const float*)d_in[6];
  const float* W2 = (const float*)d_in[7];
  const float* lns = (const float*)d_in[8];
  const float* lnb = (const float*)d_in[9];
  const float* gns = (const float*)d_in[10];
  const float* gnb = (const float*)d_in[11];
  float* out = (float*)d_out;

  char* W = (char*)d_ws;
  const size_t MB = 1u << 20;
  float* Abuf = (float*)(W);            // 16 MB fp32
  short* Xnb  = (short*)(W + 16 * MB);  // 8 MB bf16
  float* Qf   = (float*)(W + 24 * MB);  // 16 MB fp32 (later Y0)
  float* Kf   = (float*)(W + 40 * MB);  // 16 MB fp32 (later Y1)
  short* Vb   = (short*)(W + 56 * MB);  // 8 MB bf16 (later gate out Gb)
  short* Graw = (short*)(W + 64 * MB);  // 8 MB bf16
  short* Qb2  = (short*)(W + 72 * MB);  // 8 MB bf16 (Hb aliases 72..88)
  short* Kb2  = (short*)(W + 80 * MB);  // 8 MB bf16
  short* Vtb  = (short*)(W + 88 * MB);  // 8 MB bf16
  short* Wqkvgt = (short*)(W + 96 * MB);   // 8 MB
  short* Wot  = (short*)(W + 104 * MB);    // 2 MB
  short* W1t  = (short*)(W + 106 * MB);    // 4 MB
  short* W2t  = (short*)(W + 110 * MB);    // 4 MB
  float* ct   = (float*)(W + 114 * MB);    // 256 KB
  float* st   = ct + Ss * 64;              // 256 KB
  float* Y0 = Qf;
  float* Y1 = Kf;
  short* Gb = Vb;
  short* Hb = Qb2;  // 16 MB (Qb2+Kb2 region)

  hipMemcpyAsync(Abuf, X, (size_t)Mm * Dd * sizeof(float), hipMemcpyDeviceToDevice, stream);
  rope_table_kernel<<<(Ss * 64) / 256, 256, 0, stream>>>(ct, st);

  for (int l = 0; l < LAYERS; ++l) {
    const size_t DD = (size_t)Dd * Dd;
    wtrans4_kernel<<<dim3(128, 32), 256, 0, stream>>>(Wq + l * DD, Wk + l * DD, Wv + l * DD,
                                                      Wg + l * DD, Wqkvgt);
    wtrans1_kernel<<<dim3(32, 32), 256, 0, stream>>>(Wo + l * DD, Wot, Dd, Dd);
    wtrans1_kernel<<<dim3(64, 32), 256, 0, stream>>>(W1 + (size_t)l * Dd * Ff, W1t, Dd, Ff);
    wtrans1_kernel<<<dim3(32, 64), 256, 0, stream>>>(W2 + (size_t)l * Ff * Dd, W2t, Ff, Dd);

    // Xn = LN(A) -> bf16
    ln_bf16_kernel<<<Mm, 256, 0, stream>>>(Abuf, Xnb, lns, lnb);
    // fused QKVG projection (N=4096): 256x256 tiles, 256 blocks
    gemm5<256, 256, 2, 4, 0><<<dim3(16, 16), 512, 0, stream>>>(
        Xnb, Wqkvgt, nullptr, nullptr, nullptr, Qf, Kf, Vb, Graw, 4096, Dd);
    // RoPE Q,K -> bf16
    rope_bf16_kernel<<<(Bb * Ss * Hh * 64) / 256, 256, 0, stream>>>(Qf, Kf, Qb2, Kb2, ct, st);
    // V transpose
    vtrans16_kernel<<<dim3(Ss / 32, DHd / 32, Bb * Hh), 256, 0, stream>>>(Vb, Vtb);
    // retention -> partial Y0,Y1 (fp32)
    ret4_kernel<<<512, 256, 0, stream>>>(Qb2, Kb2, Vtb, Y0, Y1);
    // gate: Gb = swish(Graw) * GN(Y0+Y1)
    gate_kernel<<<(Mm * Hh) / 4, 256, 0, stream>>>(Y0, Y1, Graw, Gb,
                                                   gns + (size_t)l * Dd, gnb + (size_t)l * Dd);
    // A = (Gb @ Wo) + A  : 128x128 tiles, 256 blocks
    gemm5<128, 128, 2, 2, 1><<<dim3(8, 32), 256, 0, stream>>>(
        Gb, Wot, Abuf, nullptr, Abuf, nullptr, nullptr, nullptr, nullptr, Dd, Dd);
    // FFN
    ln_bf16_kernel<<<Mm, 256, 0, stream>>>(Abuf, Xnb, lns, lnb);
    gemm5<256, 128, 2, 4, 2><<<dim3(16, 16), 512, 0, stream>>>(
        Xnb, W1t, nullptr, Hb, nullptr, nullptr, nullptr, nullptr, nullptr, Ff, Dd);
    float* dst = (l == LAYERS - 1) ? out : Abuf;
    gemm5<128, 128, 2, 2, 1><<<dim3(8, 32), 256, 0, stream>>>(
        Hb, W2t, dst, nullptr, Abuf, nullptr, nullptr, nullptr, nullptr, Dd, Ff);
  }
}

// Round 6
// 985.900 us; speedup vs baseline: 1.0098x; 1.0098x over previous
//
#include <hip/hip_runtime.h>
#include <hip/hip_bf16.h>
#include <cmath>

#define LAYERS 4
#define Bb 4
#define Ss 1024
#define Dd 1024
#define Ff 2048
#define Hh 8
#define DHd 128
#define Mm (Bb * Ss)   // 4096 rows
#define EPSf 1e-5f

typedef __attribute__((ext_vector_type(8))) short short8v;
typedef __attribute__((ext_vector_type(4))) float f32x4;
typedef __attribute__((ext_vector_type(4))) unsigned int u32x4;

__device__ __forceinline__ float swish_f(float x) { return x / (1.f + expf(-x)); }
__device__ __forceinline__ float gelu_f(float x) {
  return 0.5f * x * (1.f + tanhf(0.7978845608028654f * (x + 0.044715f * x * x * x)));
}
__device__ __forceinline__ unsigned short f2bfu(float f) {
  __hip_bfloat16 h = __float2bfloat16(f);
  return __builtin_bit_cast(unsigned short, h);
}
__device__ __forceinline__ float bfu2f(unsigned short u) {
  unsigned v = ((unsigned)u) << 16;
  return __builtin_bit_cast(float, v);
}
__device__ __forceinline__ void gl_lds16(const void* g, void* l) {
  __builtin_amdgcn_global_load_lds((__attribute__((address_space(1))) void*)g,
                                   (__attribute__((address_space(3))) void*)l, 16, 0, 0);
}
__device__ __forceinline__ f32x4 mfma16(short8v a, short8v b, f32x4 c) {
  return __builtin_amdgcn_mfma_f32_16x16x32_bf16(a, b, c, 0, 0, 0);
}

// ---------------- LayerNorm fp32 -> bf16 ----------------
__global__ __launch_bounds__(256) void ln_bf16_kernel(const float* __restrict__ x,
                                                      short* __restrict__ outb,
                                                      const float* __restrict__ sc,
                                                      const float* __restrict__ bi) {
  const int row = blockIdx.x;
  const int t = threadIdx.x;
  const float4 v = *(const float4*)(x + (size_t)row * Dd + t * 4);
  float s = v.x + v.y + v.z + v.w;
  float s2 = v.x * v.x + v.y * v.y + v.z * v.z + v.w * v.w;
#pragma unroll
  for (int o = 32; o > 0; o >>= 1) { s += __shfl_down(s, o); s2 += __shfl_down(s2, o); }
  __shared__ float ps[4], ps2[4];
  if ((t & 63) == 0) { ps[t >> 6] = s; ps2[t >> 6] = s2; }
  __syncthreads();
  s = ps[0] + ps[1] + ps[2] + ps[3];
  s2 = ps2[0] + ps2[1] + ps2[2] + ps2[3];
  const float mu = s * (1.f / Dd);
  const float var = s2 * (1.f / Dd) - mu * mu;
  const float rstd = rsqrtf(var + EPSf);
  const float4 g = *(const float4*)(sc + t * 4);
  const float4 b = *(const float4*)(bi + t * 4);
  const float o0 = (v.x - mu) * rstd * g.x + b.x;
  const float o1 = (v.y - mu) * rstd * g.y + b.y;
  const float o2 = (v.z - mu) * rstd * g.z + b.z;
  const float o3 = (v.w - mu) * rstd * g.w + b.w;
  unsigned p0 = (unsigned)f2bfu(o0) | ((unsigned)f2bfu(o1) << 16);
  unsigned p1 = (unsigned)f2bfu(o2) | ((unsigned)f2bfu(o3) << 16);
  uint2 pk; pk.x = p0; pk.y = p1;
  *(uint2*)(outb + (size_t)row * Dd + t * 4) = pk;
}

// ---------------- RoPE tables ----------------
__global__ void rope_table_kernel(float* __restrict__ ct, float* __restrict__ st) {
  const int i = blockIdx.x * 256 + threadIdx.x;  // < Ss*64
  const int s = i >> 6, f = i & 63;
  const float inv = powf(10000.f, -(float)f / 64.f);
  const float a = (float)s * inv;
  ct[i] = cosf(a);
  st[i] = sinf(a);
}

// ---------------- transpose-convert QKVG concat: 4x W[K][1024] fp32 -> Wt[4096][K] bf16 ----
__global__ __launch_bounds__(256) void wtrans4_kernel(const float* __restrict__ W0,
                                                      const float* __restrict__ W1,
                                                      const float* __restrict__ W2,
                                                      const float* __restrict__ W3,
                                                      short* __restrict__ Wt) {
  __shared__ float tile[32][33];
  const int t = threadIdx.x;
  const int n0 = blockIdx.x * 32, k0 = blockIdx.y * 32;
  const int which = n0 >> 10;
  const float* W = (which == 0) ? W0 : (which == 1) ? W1 : (which == 2) ? W2 : W3;
  const int nl = n0 & 1023;
  const int tc = t & 31, tr8 = t >> 5;
#pragma unroll
  for (int i = 0; i < 4; ++i) {
    const int r = tr8 + i * 8;
    tile[r][tc] = W[(size_t)(k0 + r) * 1024 + nl + tc];
  }
  __syncthreads();
#pragma unroll
  for (int i = 0; i < 4; ++i) {
    const int r = tr8 + i * 8;
    Wt[(size_t)(n0 + r) * 1024 + k0 + tc] = (short)f2bfu(tile[tc][r]);
  }
}

// ---------------- transpose-convert single: W[K][N] fp32 -> Wt[N][K] bf16 ----------------
__global__ __launch_bounds__(256) void wtrans1_kernel(const float* __restrict__ W,
                                                      short* __restrict__ Wt, int K, int N) {
  __shared__ float tile[32][33];
  const int t = threadIdx.x;
  const int n0 = blockIdx.x * 32, k0 = blockIdx.y * 32;
  const int tc = t & 31, tr8 = t >> 5;
#pragma unroll
  for (int i = 0; i < 4; ++i) {
    const int r = tr8 + i * 8;
    tile[r][tc] = W[(size_t)(k0 + r) * N + n0 + tc];
  }
  __syncthreads();
#pragma unroll
  for (int i = 0; i < 4; ++i) {
    const int r = tr8 + i * 8;
    Wt[(size_t)(n0 + r) * K + k0 + tc] = (short)f2bfu(tile[tc][r]);
  }
}

// ---------------- V transpose bf16: Vb [B*S][D-slice h] -> Vt [(bh*128+d)][S] ----------------
__global__ __launch_bounds__(256) void vtrans16_kernel(const short* __restrict__ Vb,
                                                       short* __restrict__ Vt) {
  __shared__ short tile[32][33];
  const int t = threadIdx.x;
  const int s0 = blockIdx.x * 32, d0 = blockIdx.y * 32, bh = blockIdx.z;
  const int bb = bh >> 3, h = bh & 7;
  const int tc = t & 31, tr8 = t >> 5;
#pragma unroll
  for (int i = 0; i < 4; ++i) {
    const int r = tr8 + i * 8;
    tile[r][tc] = Vb[(size_t)(bb * Ss + s0 + r) * Dd + h * DHd + d0 + tc];
  }
  __syncthreads();
#pragma unroll
  for (int i = 0; i < 4; ++i) {
    const int r = tr8 + i * 8;
    Vt[(size_t)(bh * DHd + d0 + r) * Ss + s0 + tc] = tile[tc][r];
  }
}

// ---------------- bf16 MFMA GEMM v6: ring-4 LDS, counted vmcnt, fixed XOR swizzle ---------
// swizzle: LDS chunk slot = sc ^ ((row>>1)&3) (2-way residual = free). RoPE fused in EPI 0.
// EPI: 0 = QKVG route (Q,K: RoPE->bf16; V,G bf16), 1 = +Res fp32, 2 = gelu bf16
template <int BM, int BN, int NWM, int NWC, int EPI>
__global__ __launch_bounds__(NWM * NWC * 64) void gemm6(
    const short* __restrict__ A, const short* __restrict__ Bt,
    float* __restrict__ Cf, short* __restrict__ Cb, const float* __restrict__ Res,
    short* __restrict__ Qo, short* __restrict__ Ko,
    short* __restrict__ Vb, short* __restrict__ Gb,
    const float* __restrict__ ctp, const float* __restrict__ stp, int N, int K) {
  constexpr int NTHR = NWM * NWC * 64;
  constexpr int WM = BM / NWM, WN = BN / NWC;
  constexpr int MR = WM / 16, NR = WN / 16;
  constexpr int LA = (BM * 4) / NTHR, LB = (BN * 4) / NTHR;
  constexpr int LT = LA + LB;
  __shared__ __align__(16) short As[4][BM * 32];
  __shared__ __align__(16) short Bs[4][BN * 32];
  const int t = threadIdx.x;
  const int w = t >> 6, l = t & 63;
  const int lq = l >> 4, lr = l & 15;
  const int wr = w / NWC, wc = w % NWC;
  // T1: bijective XCD swizzle (nwg % 8 == 0 for all grids here)
  const int nwg = gridDim.x * gridDim.y;
  const int bid0 = blockIdx.x + blockIdx.y * gridDim.x;
  const int lgid = (bid0 & 7) * (nwg >> 3) + (bid0 >> 3);
  const int bx = lgid % gridDim.x, by = lgid / gridDim.x;
  const int row0 = by * BM, col0 = bx * BN;
  f32x4 acc[MR][NR] = {};
  const int NTK = K >> 5;

  auto stage = [&](int tile) {
    const int rg = tile & 3;
    const int k0 = tile << 5;
#pragma unroll
    for (int i = 0; i < LA; ++i) {
      const int c = t + i * NTHR;
      const int row = c >> 2, sc = c & 3;
      gl_lds16(A + (size_t)(row0 + row) * K + k0 + ((sc ^ ((row >> 1) & 3)) << 3),
               &As[rg][(w * 64 + i * NTHR) * 8]);
    }
#pragma unroll
    for (int i = 0; i < LB; ++i) {
      const int c = t + i * NTHR;
      const int row = c >> 2, sc = c & 3;
      gl_lds16(Bt + (size_t)(col0 + row) * K + k0 + ((sc ^ ((row >> 1) & 3)) << 3),
               &Bs[rg][(w * 64 + i * NTHR) * 8]);
    }
  };

  stage(0); stage(1); stage(2);
  for (int tt = 0; tt < NTK; ++tt) {
    const int rem = NTK - 1 - tt;
    if (rem >= 2) {
      asm volatile("s_waitcnt vmcnt(%0)\n\ts_barrier" :: "n"(2 * LT) : "memory");
    } else if (rem == 1) {
      asm volatile("s_waitcnt vmcnt(%0)\n\ts_barrier" :: "n"(LT) : "memory");
    } else {
      asm volatile("s_waitcnt vmcnt(0)\n\ts_barrier" ::: "memory");
    }
    if (tt + 3 < NTK) stage(tt + 3);  // overwrites slot of tile tt-1 (reads done pre-barrier)
    const int rg = tt & 3;
    short8v a[MR], b[NR];
#pragma unroll
    for (int m = 0; m < MR; ++m) {
      const int row = wr * WM + m * 16 + lr;
      a[m] = *(const short8v*)&As[rg][row * 32 + ((lq ^ ((row >> 1) & 3)) << 3)];
    }
#pragma unroll
    for (int n = 0; n < NR; ++n) {
      const int col = wc * WN + n * 16 + lr;
      b[n] = *(const short8v*)&Bs[rg][col * 32 + ((lq ^ ((col >> 1) & 3)) << 3)];
    }
    __builtin_amdgcn_s_setprio(1);
#pragma unroll
    for (int m = 0; m < MR; ++m)
#pragma unroll
      for (int n = 0; n < NR; ++n) acc[m][n] = mfma16(a[m], b[n], acc[m][n]);
    __builtin_amdgcn_s_setprio(0);
  }

  const int sel = col0 >> 10;  // for EPI 0
  const int clb = col0 & 1023;
#pragma unroll
  for (int m = 0; m < MR; ++m) {
#pragma unroll
    for (int n = 0; n < NR; ++n) {
#pragma unroll
      for (int r = 0; r < 4; ++r) {
        const int row = row0 + wr * WM + m * 16 + lq * 4 + r;
        const int col = col0 + wc * WN + n * 16 + lr;
        float v = acc[m][n][r];
        if (EPI == 0) {
          const int cl = clb + wc * WN + n * 16 + lr;
          const size_t o = (size_t)row * 1024 + cl;
          if (sel <= 1) {
            // fused RoPE: partner element (cl^1) lives in lane lr^1, same row
            const float px = __shfl_xor(v, 1);
            const int spos = row & (Ss - 1);
            const int f = (cl >> 1) & 63;
            const float cc = ctp[(spos << 6) + f];
            const float ssn = stp[(spos << 6) + f];
            float ov;
            if (sel == 0) ov = v * cc + ((lr & 1) ? px * ssn : -px * ssn);
            else          ov = v * cc + ((lr & 1) ? -px * ssn : px * ssn);
            if (sel == 0) Qo[o] = (short)f2bfu(ov);
            else          Ko[o] = (short)f2bfu(ov);
          } else if (sel == 2) {
            Vb[o] = (short)f2bfu(v);
          } else {
            Gb[o] = (short)f2bfu(v);
          }
        } else {
          const size_t o = (size_t)row * N + col;
          if (EPI == 1) Cf[o] = v + Res[o];
          else Cb[o] = (short)f2bfu(gelu_f(v));
        }
      }
    }
  }
}

// ---------------- Retention v4: dbuf K/V, 1 barrier/tile, setprio, XCD-local bh ----------
__global__ __launch_bounds__(256) void ret4_kernel(const short* __restrict__ Qb,
                                                   const short* __restrict__ Kb,
                                                   const short* __restrict__ Vt,
                                                   float* __restrict__ Y0,
                                                   float* __restrict__ Y1) {
  __shared__ __align__(16) short Ks[2][64 * 128];
  __shared__ __align__(16) short Vs[2][128 * 64];
  const int t = threadIdx.x, w = t >> 6, l = t & 63;
  const int lq = l >> 4, lr = l & 15;
  const int u = blockIdx.x;                 // 0..511
  const int lgid = (u & 7) * 64 + (u >> 3);
  const int half = lgid >> 8;
  const int rest = lgid & 255;
  const int bh = rest >> 3, j = rest & 7;
  const int qb = half ? j : 7 - j;          // dispatch-order-balanced triangular pairing
  const int b = bh >> 3, h = bh & 7;
  const int q0 = qb * 128;
  const float lstep = (logf(1.f / 512.f) - logf(1.f / 32.f)) * (1.f / 7.f);
  const float gamma = 1.f - expf(logf(1.f / 32.f) + (float)h * lstep);
  const float l2g = logf(gamma) * 1.44269504f;  // log2(gamma)

  short8v qf[2][4];
#pragma unroll
  for (int qn = 0; qn < 2; ++qn)
#pragma unroll
    for (int ks = 0; ks < 4; ++ks)
      qf[qn][ks] = *(const short8v*)(Qb + (size_t)(b * Ss + q0 + w * 32 + qn * 16 + lr) * Dd +
                                     h * DHd + ks * 32 + lq * 8);

  float cmf[4], csr[4];
#pragma unroll
  for (int mf = 0; mf < 4; ++mf) cmf[mf] = exp2f(l2g * (float)(-16 * mf));
#pragma unroll
  for (int r = 0; r < 4; ++r) csr[r] = exp2f(l2g * (float)(63 - 4 * lq - r));

  f32x4 yacc[2][8] = {};
  const int nt = 2 * qb + 2;
  const int sb = ((lq & 1) * 2) * 16 + lr;

  auto stageKV = [&](int m0, int buf) {
#pragma unroll
    for (int i = 0; i < 4; ++i) {
      const int c = (w * 4 + i) * 64 + l;
      const int row = c >> 4, slot = c & 15;
      gl_lds16(Kb + (size_t)(b * Ss + m0 + row) * Dd + h * DHd + ((slot ^ (row & 7)) * 8),
               &Ks[buf][(w * 4 + i) * 512]);
    }
#pragma unroll
    for (int i = 0; i < 4; ++i) {
      const int c = (w * 4 + i) * 64 + l;
      const int row = c >> 3, slot = c & 7;
      gl_lds16(Vt + (size_t)(bh * DHd + row) * Ss + m0 + ((slot ^ (row & 7)) * 8),
               &Vs[buf][(w * 4 + i) * 512]);
    }
  };

  stageKV(half * 64, 0);
  __syncthreads();
  int cur = 0;
  for (int tt = half; tt < nt; tt += 2) {
    const int m0 = tt * 64;
    if (tt + 2 < nt) stageKV((tt + 2) * 64, cur ^ 1);

    f32x4 st[4][2] = {};
    __builtin_amdgcn_s_setprio(1);
#pragma unroll
    for (int mf = 0; mf < 4; ++mf) {
      const int row = mf * 16 + lr;
#pragma unroll
      for (int ks = 0; ks < 4; ++ks) {
        short8v kf = *(const short8v*)&Ks[cur][row * 128 + (((4 * ks + lq) ^ (row & 7)) * 8)];
        st[mf][0] = mfma16(kf, qf[0][ks], st[mf][0]);
        st[mf][1] = mfma16(kf, qf[1][ks], st[mf][1]);
      }
    }
    __builtin_amdgcn_s_setprio(0);
    float rs[2];
#pragma unroll
    for (int qn = 0; qn < 2; ++qn)
      rs[qn] = exp2f(l2g * (float)(q0 + w * 32 + qn * 16 + lr - m0 - 63));
#pragma unroll
    for (int mf = 0; mf < 4; ++mf)
#pragma unroll
      for (int qn = 0; qn < 2; ++qn)
#pragma unroll
        for (int r = 0; r < 4; ++r) {
          const int qg = q0 + w * 32 + qn * 16 + lr;
          const int kvg = m0 + mf * 16 + lq * 4 + r;
          const float wgt = (qg >= kvg) ? rs[qn] * cmf[mf] * csr[r] : 0.f;
          st[mf][qn][r] *= wgt;
        }
    unsigned pk[4][2][2];
#pragma unroll
    for (int mf = 0; mf < 4; ++mf)
#pragma unroll
      for (int qn = 0; qn < 2; ++qn)
#pragma unroll
        for (int p = 0; p < 2; ++p)
          pk[mf][qn][p] = (unsigned)f2bfu(st[mf][qn][2 * p]) |
                          ((unsigned)f2bfu(st[mf][qn][2 * p + 1]) << 16);
    short8v afr[2][2];
#pragma unroll
    for (int qn = 0; qn < 2; ++qn)
#pragma unroll
      for (int ks2 = 0; ks2 < 2; ++ks2) {
        u32x4 wd;
#pragma unroll
        for (int wj = 0; wj < 4; ++wj) {
          const int src = sb + (wj >> 1) * 16;
          const unsigned v0 = __shfl(pk[2 * ks2 + 0][qn][wj & 1], src);
          const unsigned v1 = __shfl(pk[2 * ks2 + 1][qn][wj & 1], src);
          wd[wj] = (lq >= 2) ? v1 : v0;
        }
        afr[qn][ks2] = __builtin_bit_cast(short8v, wd);
      }
    __builtin_amdgcn_s_setprio(1);
#pragma unroll
    for (int nd = 0; nd < 8; ++nd) {
      const int row = nd * 16 + lr;
#pragma unroll
      for (int ks2 = 0; ks2 < 2; ++ks2) {
        short8v vf = *(const short8v*)&Vs[cur][row * 64 + (((4 * ks2 + lq) ^ (row & 7)) * 8)];
        yacc[0][nd] = mfma16(afr[0][ks2], vf, yacc[0][nd]);
        yacc[1][nd] = mfma16(afr[1][ks2], vf, yacc[1][nd]);
      }
    }
    __builtin_amdgcn_s_setprio(0);
    __syncthreads();
    cur ^= 1;
  }
  float* Y = half ? Y1 : Y0;
#pragma unroll
  for (int qn = 0; qn < 2; ++qn)
#pragma unroll
    for (int r = 0; r < 4; ++r) {
      const int q = q0 + w * 32 + qn * 16 + lq * 4 + r;
#pragma unroll
      for (int nd = 0; nd < 8; ++nd)
        Y[(size_t)(b * Ss + q) * Dd + h * DHd + nd * 16 + lr] = yacc[qn][nd][r];
    }
}

// ---------------- gate: Gb = bf16( swish(Graw) * GN(Y0+Y1) ) ----------------
__global__ __launch_bounds__(256) void gate_kernel(const float* __restrict__ Y0,
                                                   const float* __restrict__ Y1,
                                                   const short* __restrict__ Graw,
                                                   short* __restrict__ Gb,
                                                   const float* __restrict__ gs,
                                                   const float* __restrict__ gb) {
  const int lane = threadIdx.x & 63;
  const int rowh = blockIdx.x * 4 + (threadIdx.x >> 6);  // (b*S+s)*H + h
  const int h = rowh & 7;
  const size_t base = (size_t)(rowh >> 3) * Dd + (size_t)h * DHd + lane * 2;
  float2 a = *(const float2*)(Y0 + base);
  const float2 c = *(const float2*)(Y1 + base);
  a.x += c.x; a.y += c.y;
  float s = a.x + a.y, s2 = a.x * a.x + a.y * a.y;
#pragma unroll
  for (int o = 32; o > 0; o >>= 1) { s += __shfl_down(s, o); s2 += __shfl_down(s2, o); }
  s = __shfl(s, 0);
  s2 = __shfl(s2, 0);
  const float mu = s * (1.f / DHd);
  const float rstd = rsqrtf(s2 * (1.f / DHd) - mu * mu + EPSf);
  const int d = h * DHd + lane * 2;
  const float2 g = *(const float2*)(gs + d);
  const float2 bbv = *(const float2*)(gb + d);
  const float y0 = (a.x - mu) * rstd * g.x + bbv.x;
  const float y1 = (a.y - mu) * rstd * g.y + bbv.y;
  const unsigned gr = *(const unsigned*)(Graw + base);
  const float gx = bfu2f((unsigned short)(gr & 0xffff));
  const float gy = bfu2f((unsigned short)(gr >> 16));
  const unsigned o01 = (unsigned)f2bfu(swish_f(gx) * y0) |
                       ((unsigned)f2bfu(swish_f(gy) * y1) << 16);
  *(unsigned*)(Gb + base) = o01;
}

extern "C" void kernel_launch(void* const* d_in, const int* in_sizes, int n_in,
                              void* d_out, int out_size, void* d_ws, size_t ws_size,
                              hipStream_t stream) {
  const float* X = (const float*)d_in[0];
  const float* Wq = (const float*)d_in[1];
  const float* Wk = (const float*)d_in[2];
  const float* Wv = (const float*)d_in[3];
  const float* Wg = (const float*)d_in[4];
  const float* Wo = (const float*)d_in[5];
  const float* W1 = (const float*)d_in[6];
  const float* W2 = (const float*)d_in[7];
  const float* lns = (const float*)d_in[8];
  const float* lnb = (const float*)d_in[9];
  const float* gns = (const float*)d_in[10];
  const float* gnb = (const float*)d_in[11];
  float* out = (float*)d_out;

  char* W = (char*)d_ws;
  const size_t MB = 1u << 20;
  float* Abuf = (float*)(W);            // 16 MB fp32
  short* Xnb  = (short*)(W + 16 * MB);  // 8 MB bf16
  float* Y0   = (float*)(W + 24 * MB);  // 16 MB fp32
  float* Y1   = (float*)(W + 40 * MB);  // 16 MB fp32
  short* Vb   = (short*)(W + 56 * MB);  // 8 MB bf16 (later gate out Gb)
  short* Graw = (short*)(W + 64 * MB);  // 8 MB bf16
  short* Qb2  = (short*)(W + 72 * MB);  // 8 MB bf16 (Hb aliases 72..88)
  short* Kb2  = (short*)(W + 80 * MB);  // 8 MB bf16
  short* Vtb  = (short*)(W + 88 * MB);  // 8 MB bf16
  short* Wqkvgt = (short*)(W + 96 * MB);   // 8 MB
  short* Wot  = (short*)(W + 104 * MB);    // 2 MB
  short* W1t  = (short*)(W + 106 * MB);    // 4 MB
  short* W2t  = (short*)(W + 110 * MB);    // 4 MB
  float* ct   = (float*)(W + 114 * MB);    // 256 KB
  float* st   = ct + Ss * 64;              // 256 KB
  short* Gb = Vb;
  short* Hb = Qb2;  // 16 MB (Qb2+Kb2 region)

  hipMemcpyAsync(Abuf, X, (size_t)Mm * Dd * sizeof(float), hipMemcpyDeviceToDevice, stream);
  rope_table_kernel<<<(Ss * 64) / 256, 256, 0, stream>>>(ct, st);

  for (int l = 0; l < LAYERS; ++l) {
    const size_t DD = (size_t)Dd * Dd;
    wtrans4_kernel<<<dim3(128, 32), 256, 0, stream>>>(Wq + l * DD, Wk + l * DD, Wv + l * DD,
                                                      Wg + l * DD, Wqkvgt);
    wtrans1_kernel<<<dim3(32, 32), 256, 0, stream>>>(Wo + l * DD, Wot, Dd, Dd);
    wtrans1_kernel<<<dim3(64, 32), 256, 0, stream>>>(W1 + (size_t)l * Dd * Ff, W1t, Dd, Ff);
    wtrans1_kernel<<<dim3(32, 64), 256, 0, stream>>>(W2 + (size_t)l * Ff * Dd, W2t, Ff, Dd);

    // Xn = LN(A) -> bf16
    ln_bf16_kernel<<<Mm, 256, 0, stream>>>(Abuf, Xnb, lns, lnb);
    // fused QKVG projection (N=4096) with fused RoPE -> Qb2,Kb2 bf16; V,G bf16
    gemm6<256, 256, 2, 4, 0><<<dim3(16, 16), 512, 0, stream>>>(
        Xnb, Wqkvgt, nullptr, nullptr, nullptr, Qb2, Kb2, Vb, Graw, ct, st, 4096, Dd);
    // V transpose
    vtrans16_kernel<<<dim3(Ss / 32, DHd / 32, Bb * Hh), 256, 0, stream>>>(Vb, Vtb);
    // retention -> partial Y0,Y1 (fp32)
    ret4_kernel<<<512, 256, 0, stream>>>(Qb2, Kb2, Vtb, Y0, Y1);
    // gate: Gb = swish(Graw) * GN(Y0+Y1)
    gate_kernel<<<(Mm * Hh) / 4, 256, 0, stream>>>(Y0, Y1, Graw, Gb,
                                                   gns + (size_t)l * Dd, gnb + (size_t)l * Dd);
    // A = (Gb @ Wo) + A  : 128x128 tiles, 256 blocks, ring-4 (64 KB -> 2 blocks/CU)
    gemm6<128, 128, 2, 2, 1><<<dim3(8, 32), 256, 0, stream>>>(
        Gb, Wot, Abuf, nullptr, Abuf, nullptr, nullptr, nullptr, nullptr, nullptr, nullptr,
        Dd, Dd);
    // FFN
    ln_bf16_kernel<<<Mm, 256, 0, stream>>>(Abuf, Xnb, lns, lnb);
    gemm6<256, 128, 2, 4, 2><<<dim3(16, 16), 512, 0, stream>>>(
        Xnb, W1t, nullptr, Hb, nullptr, nullptr, nullptr, nullptr, nullptr, nullptr, nullptr,
        Ff, Dd);
    float* dst = (l == LAYERS - 1) ? out : Abuf;
    gemm6<128, 128, 2, 2, 1><<<dim3(8, 32), 256, 0, stream>>>(
        Hb, W2t, dst, nullptr, Abuf, nullptr, nullptr, nullptr, nullptr, nullptr, nullptr,
        Dd, Ff);
  }
}

// Round 7
// 907.954 us; speedup vs baseline: 1.0965x; 1.0858x over previous
//
#include <hip/hip_runtime.h>
#include <hip/hip_bf16.h>
#include <cmath>

#define LAYERS 4
#define Bb 4
#define Ss 1024
#define Dd 1024
#define Ff 2048
#define Hh 8
#define DHd 128
#define Mm (Bb * Ss)   // 4096 rows
#define EPSf 1e-5f
#define LDQ 4096       // combined QKVG row stride

typedef __attribute__((ext_vector_type(8))) short short8v;
typedef __attribute__((ext_vector_type(4))) float f32x4;
typedef __attribute__((ext_vector_type(4))) unsigned int u32x4;

__device__ __forceinline__ float swish_f(float x) { return x / (1.f + expf(-x)); }
__device__ __forceinline__ float gelu_f(float x) {
  return 0.5f * x * (1.f + tanhf(0.7978845608028654f * (x + 0.044715f * x * x * x)));
}
__device__ __forceinline__ unsigned short f2bfu(float f) {
  __hip_bfloat16 h = __float2bfloat16(f);
  return __builtin_bit_cast(unsigned short, h);
}
__device__ __forceinline__ float bfu2f(unsigned short u) {
  unsigned v = ((unsigned)u) << 16;
  return __builtin_bit_cast(float, v);
}
__device__ __forceinline__ void gl_lds16(const void* g, void* l) {
  __builtin_amdgcn_global_load_lds((__attribute__((address_space(1))) void*)g,
                                   (__attribute__((address_space(3))) void*)l, 16, 0, 0);
}
__device__ __forceinline__ f32x4 mfma16(short8v a, short8v b, f32x4 c) {
  return __builtin_amdgcn_mfma_f32_16x16x32_bf16(a, b, c, 0, 0, 0);
}

// ---------------- LayerNorm fp32 -> bf16 ----------------
__global__ __launch_bounds__(256) void ln_bf16_kernel(const float* __restrict__ x,
                                                      short* __restrict__ outb,
                                                      const float* __restrict__ sc,
                                                      const float* __restrict__ bi) {
  const int row = blockIdx.x;
  const int t = threadIdx.x;
  const float4 v = *(const float4*)(x + (size_t)row * Dd + t * 4);
  float s = v.x + v.y + v.z + v.w;
  float s2 = v.x * v.x + v.y * v.y + v.z * v.z + v.w * v.w;
#pragma unroll
  for (int o = 32; o > 0; o >>= 1) { s += __shfl_down(s, o); s2 += __shfl_down(s2, o); }
  __shared__ float ps[4], ps2[4];
  if ((t & 63) == 0) { ps[t >> 6] = s; ps2[t >> 6] = s2; }
  __syncthreads();
  s = ps[0] + ps[1] + ps[2] + ps[3];
  s2 = ps2[0] + ps2[1] + ps2[2] + ps2[3];
  const float mu = s * (1.f / Dd);
  const float var = s2 * (1.f / Dd) - mu * mu;
  const float rstd = rsqrtf(var + EPSf);
  const float4 g = *(const float4*)(sc + t * 4);
  const float4 b = *(const float4*)(bi + t * 4);
  const float o0 = (v.x - mu) * rstd * g.x + b.x;
  const float o1 = (v.y - mu) * rstd * g.y + b.y;
  const float o2 = (v.z - mu) * rstd * g.z + b.z;
  const float o3 = (v.w - mu) * rstd * g.w + b.w;
  unsigned p0 = (unsigned)f2bfu(o0) | ((unsigned)f2bfu(o1) << 16);
  unsigned p1 = (unsigned)f2bfu(o2) | ((unsigned)f2bfu(o3) << 16);
  uint2 pk; pk.x = p0; pk.y = p1;
  *(uint2*)(outb + (size_t)row * Dd + t * 4) = pk;
}

// ---------------- RoPE tables ----------------
__global__ void rope_table_kernel(float* __restrict__ ct, float* __restrict__ st) {
  const int i = blockIdx.x * 256 + threadIdx.x;  // < Ss*64
  const int s = i >> 6, f = i & 63;
  const float inv = powf(10000.f, -(float)f / 64.f);
  const float a = (float)s * inv;
  ct[i] = cosf(a);
  st[i] = sinf(a);
}

// ---------------- RoPE in-place on combined bf16 QKVG buffer (Q:+sin, K:-sin) -------------
__global__ void rope_ip_kernel(short* __restrict__ QK, const float* __restrict__ ct,
                               const float* __restrict__ st) {
  const int idx = blockIdx.x * 256 + threadIdx.x;  // < B*S*H*64
  const int f = idx & 63;
  const int h = (idx >> 6) & 7;
  const int r = idx >> 9;            // b*S+s
  const int s = r & (Ss - 1);
  const float c = ct[(s << 6) + f], sn = st[(s << 6) + f];
  const size_t qo = (size_t)r * LDQ + h * DHd + 2 * f;
  const unsigned qp = *(const unsigned*)(QK + qo);
  const unsigned kp = *(const unsigned*)(QK + qo + 1024);
  const float qx = bfu2f((unsigned short)(qp & 0xffff)), qy = bfu2f((unsigned short)(qp >> 16));
  const float kx = bfu2f((unsigned short)(kp & 0xffff)), ky = bfu2f((unsigned short)(kp >> 16));
  const unsigned qn = (unsigned)f2bfu(qx * c - qy * sn) | ((unsigned)f2bfu(qx * sn + qy * c) << 16);
  const unsigned kn = (unsigned)f2bfu(kx * c + ky * sn) | ((unsigned)f2bfu(-kx * sn + ky * c) << 16);
  *(unsigned*)(QK + qo) = qn;
  *(unsigned*)(QK + qo + 1024) = kn;
}

// ---------------- transpose-convert QKVG concat: 4x W[K][1024] fp32 -> Wt[4096][K] bf16 ----
__global__ __launch_bounds__(256) void wtrans4_kernel(const float* __restrict__ W0,
                                                      const float* __restrict__ W1,
                                                      const float* __restrict__ W2,
                                                      const float* __restrict__ W3,
                                                      short* __restrict__ Wt) {
  __shared__ float tile[32][33];
  const int t = threadIdx.x;
  const int n0 = blockIdx.x * 32, k0 = blockIdx.y * 32;
  const int which = n0 >> 10;
  const float* W = (which == 0) ? W0 : (which == 1) ? W1 : (which == 2) ? W2 : W3;
  const int nl = n0 & 1023;
  const int tc = t & 31, tr8 = t >> 5;
#pragma unroll
  for (int i = 0; i < 4; ++i) {
    const int r = tr8 + i * 8;
    tile[r][tc] = W[(size_t)(k0 + r) * 1024 + nl + tc];
  }
  __syncthreads();
#pragma unroll
  for (int i = 0; i < 4; ++i) {
    const int r = tr8 + i * 8;
    Wt[(size_t)(n0 + r) * 1024 + k0 + tc] = (short)f2bfu(tile[tc][r]);
  }
}

// ---------------- transpose-convert single: W[K][N] fp32 -> Wt[N][K] bf16 ----------------
__global__ __launch_bounds__(256) void wtrans1_kernel(const float* __restrict__ W,
                                                      short* __restrict__ Wt, int K, int N) {
  __shared__ float tile[32][33];
  const int t = threadIdx.x;
  const int n0 = blockIdx.x * 32, k0 = blockIdx.y * 32;
  const int tc = t & 31, tr8 = t >> 5;
#pragma unroll
  for (int i = 0; i < 4; ++i) {
    const int r = tr8 + i * 8;
    tile[r][tc] = W[(size_t)(k0 + r) * N + n0 + tc];
  }
  __syncthreads();
#pragma unroll
  for (int i = 0; i < 4; ++i) {
    const int r = tr8 + i * 8;
    Wt[(size_t)(n0 + r) * K + k0 + tc] = (short)f2bfu(tile[tc][r]);
  }
}

// ---------------- V transpose bf16: combined buf col-slice -> Vt [(bh*128+d)][S] ----------
__global__ __launch_bounds__(256) void vtrans16_kernel(const short* __restrict__ Vb,
                                                       short* __restrict__ Vt) {
  __shared__ short tile[32][33];
  const int t = threadIdx.x;
  const int s0 = blockIdx.x * 32, d0 = blockIdx.y * 32, bh = blockIdx.z;
  const int bb = bh >> 3, h = bh & 7;
  const int tc = t & 31, tr8 = t >> 5;
#pragma unroll
  for (int i = 0; i < 4; ++i) {
    const int r = tr8 + i * 8;
    tile[r][tc] = Vb[(size_t)(bb * Ss + s0 + r) * LDQ + 2048 + h * DHd + d0 + tc];
  }
  __syncthreads();
#pragma unroll
  for (int i = 0; i < 4; ++i) {
    const int r = tr8 + i * 8;
    Vt[(size_t)(bh * DHd + d0 + r) * Ss + s0 + tc] = tile[tc][r];
  }
}

// ---------------- bf16 MFMA GEMM v7: m97 structure, dbuf-2, 32KB LDS, fixed XOR swizzle ----
// 256 threads = 4 waves (2x2). BM=128, BN in {128,64}. 4 blocks/CU at 1024-block grids.
// EPI: 0 = bf16 out, 1 = +Res fp32 out, 2 = gelu bf16 out
template <int BM, int BN, int EPI>
__global__ __launch_bounds__(256) void gemm7(const short* __restrict__ A,
                                             const short* __restrict__ Bt,
                                             float* __restrict__ Cf,
                                             short* __restrict__ Cb,
                                             const float* __restrict__ Res,
                                             int N, int K, int ldc) {
  constexpr int NTHR = 256;
  constexpr int WM = BM / 2, WN = BN / 2;
  constexpr int MR = WM / 16, NR = WN / 16;
  constexpr int LA = (BM * 4) / NTHR, LB = (BN * 4) / NTHR;
  __shared__ __align__(16) short As[2][BM * 32];
  __shared__ __align__(16) short Bs[2][BN * 32];
  const int t = threadIdx.x;
  const int w = t >> 6, l = t & 63;
  const int lq = l >> 4, lr = l & 15;
  const int wr = w >> 1, wc = w & 1;
  // T1: bijective XCD swizzle (nwg % 8 == 0 for all grids here)
  const int nwg = gridDim.x * gridDim.y;
  const int bid0 = blockIdx.x + blockIdx.y * gridDim.x;
  const int lgid = (bid0 & 7) * (nwg >> 3) + (bid0 >> 3);
  const int bx = lgid % gridDim.x, by = lgid / gridDim.x;
  const int row0 = by * BM, col0 = bx * BN;
  f32x4 acc[MR][NR] = {};
  const int NTK = K >> 5;

  auto stage = [&](int tile, int buf) {
    const int k0 = tile << 5;
#pragma unroll
    for (int i = 0; i < LA; ++i) {
      const int c = t + i * NTHR;
      const int row = c >> 2, sc = c & 3;
      gl_lds16(A + (size_t)(row0 + row) * K + k0 + ((sc ^ ((row >> 1) & 3)) << 3),
               &As[buf][c * 8]);
    }
#pragma unroll
    for (int i = 0; i < LB; ++i) {
      const int c = t + i * NTHR;
      const int row = c >> 2, sc = c & 3;
      gl_lds16(Bt + (size_t)(col0 + row) * K + k0 + ((sc ^ ((row >> 1) & 3)) << 3),
               &Bs[buf][c * 8]);
    }
  };

  stage(0, 0);
  int cur = 0;
  for (int tt = 0; tt < NTK; ++tt) {
    __syncthreads();  // drains vmcnt(0): tile tt landed; prev iter's reads complete
    if (tt + 1 < NTK) stage(tt + 1, cur ^ 1);
    short8v a[MR], b[NR];
#pragma unroll
    for (int m = 0; m < MR; ++m) {
      const int row = wr * WM + m * 16 + lr;
      a[m] = *(const short8v*)&As[cur][row * 32 + ((lq ^ ((row >> 1) & 3)) << 3)];
    }
#pragma unroll
    for (int n = 0; n < NR; ++n) {
      const int col = wc * WN + n * 16 + lr;
      b[n] = *(const short8v*)&Bs[cur][col * 32 + ((lq ^ ((col >> 1) & 3)) << 3)];
    }
    __builtin_amdgcn_s_setprio(1);
#pragma unroll
    for (int m = 0; m < MR; ++m)
#pragma unroll
      for (int n = 0; n < NR; ++n) acc[m][n] = mfma16(a[m], b[n], acc[m][n]);
    __builtin_amdgcn_s_setprio(0);
    cur ^= 1;
  }

#pragma unroll
  for (int m = 0; m < MR; ++m) {
#pragma unroll
    for (int n = 0; n < NR; ++n) {
#pragma unroll
      for (int r = 0; r < 4; ++r) {
        const int row = row0 + wr * WM + m * 16 + lq * 4 + r;
        const int col = col0 + wc * WN + n * 16 + lr;
        const size_t o = (size_t)row * ldc + col;
        float v = acc[m][n][r];
        if (EPI == 0) Cb[o] = (short)f2bfu(v);
        else if (EPI == 1) Cf[o] = v + Res[o];
        else Cb[o] = (short)f2bfu(gelu_f(v));
      }
    }
  }
}

// ---------------- Retention v4: dbuf K/V, 1 barrier/tile, setprio, XCD-local bh ----------
// Q,K read from combined QKVG buffer (stride LDQ); V^T from Vtb.
__global__ __launch_bounds__(256) void ret4_kernel(const short* __restrict__ QKb,
                                                   const short* __restrict__ Vt,
                                                   float* __restrict__ Y0,
                                                   float* __restrict__ Y1) {
  __shared__ __align__(16) short Ks[2][64 * 128];
  __shared__ __align__(16) short Vs[2][128 * 64];
  const int t = threadIdx.x, w = t >> 6, l = t & 63;
  const int lq = l >> 4, lr = l & 15;
  const int u = blockIdx.x;                 // 0..511
  const int lgid = (u & 7) * 64 + (u >> 3);
  const int half = lgid >> 8;
  const int rest = lgid & 255;
  const int bh = rest >> 3, j = rest & 7;
  const int qb = half ? j : 7 - j;          // dispatch-order-balanced triangular pairing
  const int b = bh >> 3, h = bh & 7;
  const int q0 = qb * 128;
  const float lstep = (logf(1.f / 512.f) - logf(1.f / 32.f)) * (1.f / 7.f);
  const float gamma = 1.f - expf(logf(1.f / 32.f) + (float)h * lstep);
  const float l2g = logf(gamma) * 1.44269504f;  // log2(gamma)
  const short* Qp = QKb;
  const short* Kp = QKb + 1024;

  short8v qf[2][4];
#pragma unroll
  for (int qn = 0; qn < 2; ++qn)
#pragma unroll
    for (int ks = 0; ks < 4; ++ks)
      qf[qn][ks] = *(const short8v*)(Qp + (size_t)(b * Ss + q0 + w * 32 + qn * 16 + lr) * LDQ +
                                     h * DHd + ks * 32 + lq * 8);

  float cmf[4], csr[4];
#pragma unroll
  for (int mf = 0; mf < 4; ++mf) cmf[mf] = exp2f(l2g * (float)(-16 * mf));
#pragma unroll
  for (int r = 0; r < 4; ++r) csr[r] = exp2f(l2g * (float)(63 - 4 * lq - r));

  f32x4 yacc[2][8] = {};
  const int nt = 2 * qb + 2;
  const int sb = ((lq & 1) * 2) * 16 + lr;

  auto stageKV = [&](int m0, int buf) {
#pragma unroll
    for (int i = 0; i < 4; ++i) {
      const int c = (w * 4 + i) * 64 + l;
      const int row = c >> 4, slot = c & 15;
      gl_lds16(Kp + (size_t)(b * Ss + m0 + row) * LDQ + h * DHd + ((slot ^ (row & 7)) * 8),
               &Ks[buf][(w * 4 + i) * 512]);
    }
#pragma unroll
    for (int i = 0; i < 4; ++i) {
      const int c = (w * 4 + i) * 64 + l;
      const int row = c >> 3, slot = c & 7;
      gl_lds16(Vt + (size_t)(bh * DHd + row) * Ss + m0 + ((slot ^ (row & 7)) * 8),
               &Vs[buf][(w * 4 + i) * 512]);
    }
  };

  stageKV(half * 64, 0);
  __syncthreads();
  int cur = 0;
  for (int tt = half; tt < nt; tt += 2) {
    const int m0 = tt * 64;
    if (tt + 2 < nt) stageKV((tt + 2) * 64, cur ^ 1);

    f32x4 st[4][2] = {};
    __builtin_amdgcn_s_setprio(1);
#pragma unroll
    for (int mf = 0; mf < 4; ++mf) {
      const int row = mf * 16 + lr;
#pragma unroll
      for (int ks = 0; ks < 4; ++ks) {
        short8v kf = *(const short8v*)&Ks[cur][row * 128 + (((4 * ks + lq) ^ (row & 7)) * 8)];
        st[mf][0] = mfma16(kf, qf[0][ks], st[mf][0]);
        st[mf][1] = mfma16(kf, qf[1][ks], st[mf][1]);
      }
    }
    __builtin_amdgcn_s_setprio(0);
    float rs[2];
#pragma unroll
    for (int qn = 0; qn < 2; ++qn)
      rs[qn] = exp2f(l2g * (float)(q0 + w * 32 + qn * 16 + lr - m0 - 63));
#pragma unroll
    for (int mf = 0; mf < 4; ++mf)
#pragma unroll
      for (int qn = 0; qn < 2; ++qn)
#pragma unroll
        for (int r = 0; r < 4; ++r) {
          const int qg = q0 + w * 32 + qn * 16 + lr;
          const int kvg = m0 + mf * 16 + lq * 4 + r;
          const float wgt = (qg >= kvg) ? rs[qn] * cmf[mf] * csr[r] : 0.f;
          st[mf][qn][r] *= wgt;
        }
    unsigned pk[4][2][2];
#pragma unroll
    for (int mf = 0; mf < 4; ++mf)
#pragma unroll
      for (int qn = 0; qn < 2; ++qn)
#pragma unroll
        for (int p = 0; p < 2; ++p)
          pk[mf][qn][p] = (unsigned)f2bfu(st[mf][qn][2 * p]) |
                          ((unsigned)f2bfu(st[mf][qn][2 * p + 1]) << 16);
    short8v afr[2][2];
#pragma unroll
    for (int qn = 0; qn < 2; ++qn)
#pragma unroll
      for (int ks2 = 0; ks2 < 2; ++ks2) {
        u32x4 wd;
#pragma unroll
        for (int wj = 0; wj < 4; ++wj) {
          const int src = sb + (wj >> 1) * 16;
          const unsigned v0 = __shfl(pk[2 * ks2 + 0][qn][wj & 1], src);
          const unsigned v1 = __shfl(pk[2 * ks2 + 1][qn][wj & 1], src);
          wd[wj] = (lq >= 2) ? v1 : v0;
        }
        afr[qn][ks2] = __builtin_bit_cast(short8v, wd);
      }
    __builtin_amdgcn_s_setprio(1);
#pragma unroll
    for (int nd = 0; nd < 8; ++nd) {
      const int row = nd * 16 + lr;
#pragma unroll
      for (int ks2 = 0; ks2 < 2; ++ks2) {
        short8v vf = *(const short8v*)&Vs[cur][row * 64 + (((4 * ks2 + lq) ^ (row & 7)) * 8)];
        yacc[0][nd] = mfma16(afr[0][ks2], vf, yacc[0][nd]);
        yacc[1][nd] = mfma16(afr[1][ks2], vf, yacc[1][nd]);
      }
    }
    __builtin_amdgcn_s_setprio(0);
    __syncthreads();
    cur ^= 1;
  }
  float* Y = half ? Y1 : Y0;
#pragma unroll
  for (int qn = 0; qn < 2; ++qn)
#pragma unroll
    for (int r = 0; r < 4; ++r) {
      const int q = q0 + w * 32 + qn * 16 + lq * 4 + r;
#pragma unroll
      for (int nd = 0; nd < 8; ++nd)
        Y[(size_t)(b * Ss + q) * Dd + h * DHd + nd * 16 + lr] = yacc[qn][nd][r];
    }
}

// ---------------- gate: Gb = bf16( swish(Graw) * GN(Y0+Y1) ) ----------------
__global__ __launch_bounds__(256) void gate_kernel(const float* __restrict__ Y0,
                                                   const float* __restrict__ Y1,
                                                   const short* __restrict__ Graw,
                                                   short* __restrict__ Gb,
                                                   const float* __restrict__ gs,
                                                   const float* __restrict__ gb) {
  const int lane = threadIdx.x & 63;
  const int rowh = blockIdx.x * 4 + (threadIdx.x >> 6);  // (b*S+s)*H + h
  const int h = rowh & 7;
  const int row = rowh >> 3;
  const size_t ybase = (size_t)row * Dd + (size_t)h * DHd + lane * 2;
  float2 a = *(const float2*)(Y0 + ybase);
  const float2 c = *(const float2*)(Y1 + ybase);
  a.x += c.x; a.y += c.y;
  float s = a.x + a.y, s2 = a.x * a.x + a.y * a.y;
#pragma unroll
  for (int o = 32; o > 0; o >>= 1) { s += __shfl_down(s, o); s2 += __shfl_down(s2, o); }
  s = __shfl(s, 0);
  s2 = __shfl(s2, 0);
  const float mu = s * (1.f / DHd);
  const float rstd = rsqrtf(s2 * (1.f / DHd) - mu * mu + EPSf);
  const int d = h * DHd + lane * 2;
  const float2 g = *(const float2*)(gs + d);
  const float2 bbv = *(const float2*)(gb + d);
  const float y0 = (a.x - mu) * rstd * g.x + bbv.x;
  const float y1 = (a.y - mu) * rstd * g.y + bbv.y;
  const unsigned gr = *(const unsigned*)(Graw + (size_t)row * LDQ + 3072 + h * DHd + lane * 2);
  const float gx = bfu2f((unsigned short)(gr & 0xffff));
  const float gy = bfu2f((unsigned short)(gr >> 16));
  const unsigned o01 = (unsigned)f2bfu(swish_f(gx) * y0) |
                       ((unsigned)f2bfu(swish_f(gy) * y1) << 16);
  *(unsigned*)(Gb + ybase) = o01;
}

extern "C" void kernel_launch(void* const* d_in, const int* in_sizes, int n_in,
                              void* d_out, int out_size, void* d_ws, size_t ws_size,
                              hipStream_t stream) {
  const float* X = (const float*)d_in[0];
  const float* Wq = (const float*)d_in[1];
  const float* Wk = (const float*)d_in[2];
  const float* Wv = (const float*)d_in[3];
  const float* Wg = (const float*)d_in[4];
  const float* Wo = (const float*)d_in[5];
  const float* W1 = (const float*)d_in[6];
  const float* W2 = (const float*)d_in[7];
  const float* lns = (const float*)d_in[8];
  const float* lnb = (const float*)d_in[9];
  const float* gns = (const float*)d_in[10];
  const float* gnb = (const float*)d_in[11];
  float* out = (float*)d_out;

  char* W = (char*)d_ws;
  const size_t MB = 1u << 20;
  float* Abuf  = (float*)(W);             // 16 MB fp32
  short* Xnb   = (short*)(W + 16 * MB);   // 8 MB bf16
  short* QKVGb = (short*)(W + 24 * MB);   // 32 MB bf16 [4096][4096]; Hb aliases first 16 MB
  float* Y0    = (float*)(W + 56 * MB);   // 16 MB fp32
  float* Y1    = (float*)(W + 72 * MB);   // 16 MB fp32
  short* Vtb   = (short*)(W + 88 * MB);   // 8 MB bf16
  short* Gb    = (short*)(W + 96 * MB);   // 8 MB bf16
  short* Wqkvgt= (short*)(W + 104 * MB);  // 8 MB
  short* Wot   = (short*)(W + 112 * MB);  // 2 MB
  short* W1t   = (short*)(W + 114 * MB);  // 4 MB
  short* W2t   = (short*)(W + 118 * MB);  // 4 MB
  float* ct    = (float*)(W + 122 * MB);  // 256 KB
  float* st    = ct + Ss * 64;            // 256 KB
  short* Hb = QKVGb;  // FFN hidden 4096x2048 bf16 (16 MB), G consumed by gate before W1

  hipMemcpyAsync(Abuf, X, (size_t)Mm * Dd * sizeof(float), hipMemcpyDeviceToDevice, stream);
  rope_table_kernel<<<(Ss * 64) / 256, 256, 0, stream>>>(ct, st);

  for (int l = 0; l < LAYERS; ++l) {
    const size_t DD = (size_t)Dd * Dd;
    wtrans4_kernel<<<dim3(128, 32), 256, 0, stream>>>(Wq + l * DD, Wk + l * DD, Wv + l * DD,
                                                      Wg + l * DD, Wqkvgt);
    wtrans1_kernel<<<dim3(32, 32), 256, 0, stream>>>(Wo + l * DD, Wot, Dd, Dd);
    wtrans1_kernel<<<dim3(64, 32), 256, 0, stream>>>(W1 + (size_t)l * Dd * Ff, W1t, Dd, Ff);
    wtrans1_kernel<<<dim3(32, 64), 256, 0, stream>>>(W2 + (size_t)l * Ff * Dd, W2t, Ff, Dd);

    // Xn = LN(A) -> bf16
    ln_bf16_kernel<<<Mm, 256, 0, stream>>>(Abuf, Xnb, lns, lnb);
    // fused QKVG projection -> combined bf16 buffer [4096][4096] (1024 blocks = 4/CU)
    gemm7<128, 128, 0><<<dim3(32, 32), 256, 0, stream>>>(Xnb, Wqkvgt, nullptr, QKVGb,
                                                         nullptr, 4096, Dd, LDQ);
    // RoPE in-place on Q,K slices
    rope_ip_kernel<<<(Bb * Ss * Hh * 64) / 256, 256, 0, stream>>>(QKVGb, ct, st);
    // V transpose
    vtrans16_kernel<<<dim3(Ss / 32, DHd / 32, Bb * Hh), 256, 0, stream>>>(QKVGb, Vtb);
    // retention -> partial Y0,Y1 (fp32)
    ret4_kernel<<<512, 256, 0, stream>>>(QKVGb, Vtb, Y0, Y1);
    // gate: Gb = swish(Graw) * GN(Y0+Y1)
    gate_kernel<<<(Mm * Hh) / 4, 256, 0, stream>>>(Y0, Y1, QKVGb, Gb,
                                                   gns + (size_t)l * Dd, gnb + (size_t)l * Dd);
    // A = (Gb @ Wo) + A : 128x64 tiles, 512 blocks = 2/CU
    gemm7<128, 64, 1><<<dim3(16, 32), 256, 0, stream>>>(Gb, Wot, Abuf, nullptr, Abuf,
                                                        Dd, Dd, Dd);
    // FFN
    ln_bf16_kernel<<<Mm, 256, 0, stream>>>(Abuf, Xnb, lns, lnb);
    gemm7<128, 128, 2><<<dim3(16, 32), 256, 0, stream>>>(Xnb, W1t, nullptr, Hb, nullptr,
                                                         Ff, Dd, Ff);
    float* dst = (l == LAYERS - 1) ? out : Abuf;
    gemm7<128, 64, 1><<<dim3(16, 32), 256, 0, stream>>>(Hb, W2t, dst, nullptr, Abuf,
                                                        Dd, Ff, Dd);
  }
}